// Round 8
// baseline (96.784 us; speedup 1.0000x reference)
//
#include <hip/hip_runtime.h>
#include <hip/hip_bf16.h>

#define NBINS 32
#define CHUNK 128           // voxels per chunk per block
#define NROWS 34            // bins clamped to [-1,32] then +1 -> rows 0..33; rows 1..32 = bins 0..31
#define STR 136             // halfs per row; 272B stride, 16B-aligned, bank-uniform b128 reads
#define TILE_HALVES (NROWS * STR)   // 4624 halfs = 9248 B
#define NTHREADS 256
#define NVOX 884736         // 96^3 = 6912 * 128
#define BPB 512             // grid (512,2) = 1024 blocks = exactly 4/CU
#define NSLOTS 8
#define NBLOCKS (2 * BPB)

typedef __attribute__((ext_vector_type(8))) _Float16 half8;
typedef __attribute__((ext_vector_type(16))) float f32x16;
typedef __attribute__((ext_vector_type(4))) int i32x4;

// Parzen 6-tap window — BIT-IDENTICAL math to the validated R4-R7 kernels.
__device__ __forceinline__ void compute_w(float x, int& kb, _Float16* wq) {
    float tt = x * 31.0f;
    float kf = rintf(tt);
    int ki = (int)kf;
    float u = tt - kf;               // [-0.5, 0.5]
    kb = ki - 3 + (u > 0.0f ? 1 : 0);
    float w[6];
    float s = 0.0f;
#pragma unroll
    for (int o = 0; o < 6; ++o) {
        int b = kb + o;
        float d = tt - (float)b;
        float e = __expf(-2.0f * d * d);
        e = ((unsigned)b < NBINS) ? e : 0.0f;
        w[o] = e;
        s += e;
    }
    float rinv = 1.0f / s;
#pragma unroll
    for (int o = 0; o < 6; ++o) wq[o] = (_Float16)(w[o] * rinv);
}

// Unconditional clamped writes: out-of-range taps land in garbage rows 0/33 (never read).
__device__ __forceinline__ void zero6(_Float16* __restrict__ L, int col, int kb) {
#pragma unroll
    for (int o = 0; o < 6; ++o) {
        int r = min(max(kb + o, -1), 32) + 1;
        L[r * STR + col] = (_Float16)0.0f;
    }
}
__device__ __forceinline__ void scatter6(_Float16* __restrict__ L, int col, int kb,
                                         const _Float16* wq) {
#pragma unroll
    for (int o = 0; o < 6; ++o) {
        int r = min(max(kb + o, -1), 32) + 1;
        L[r * STR + col] = wq[o];
    }
}

__global__ __launch_bounds__(NTHREADS, 4)
void mi_hist_kernel(const float* __restrict__ pred, const float* __restrict__ targ,
                    float* __restrict__ hist /* [NSLOTS][2][32][32] */,
                    int* __restrict__ counter, float* __restrict__ out) {
    __shared__ __attribute__((aligned(16))) _Float16 smem[4 * TILE_HALVES];
    __shared__ int s_last;

    const int tid = threadIdx.x;
    const int bx = blockIdx.x;
    const int batch = blockIdx.y;
    const int col = tid & 127;
    const bool isB = tid >= 128;                 // 0-127: pred tile, 128-255: targ tile
    const float* src = (isB ? targ : pred) + (size_t)batch * NVOX;
    const int toff = isB ? TILE_HALVES : 0;

    const int wid = tid >> 6;
    const int lane = tid & 63;
    // mfma_f32_32x32x16_f16: row(col)=lane&31 (bin b -> LDS row b+1), wave wid owns K [wid*32,+32)
    const int frag = (1 + (lane & 31)) * STR + wid * 32 + 8 * (lane >> 5);

    // preload ALL chunk values -> no vmem in the main loop (barriers drain nothing)
    float xs[14];
#pragma unroll
    for (int c = 0; c < 13; ++c)
        xs[c] = src[((size_t)(c * BPB + bx)) * CHUNK + col];
    const bool extra = (bx < 256);               // 6912 = 512*13 + 256, block-uniform
    if (extra) xs[13] = src[((size_t)(13 * BPB + bx)) * CHUNK + col];

    // zero all 4 tiles once
    {
        i32x4 z = {0, 0, 0, 0};
        i32x4* zp = (i32x4*)smem;
#pragma unroll
        for (int i = 0; i < 10; ++i) {
            int idx = i * NTHREADS + tid;
            if (idx < (4 * TILE_HALVES) / 8) zp[idx] = z;
        }
    }

    f32x16 acc;
#pragma unroll
    for (int r = 0; r < 16; ++r) acc[r] = 0.0f;

    int kbo0 = 0, kbo1 = 0;

#define DO_MFMA(BASE) { \
        const _Float16* Pp = (BASE); \
        _Pragma("unroll") \
        for (int kk = 0; kk < 2; ++kk) { \
            half8 af = *(const half8*)&Pp[frag + kk * 16]; \
            half8 bf = *(const half8*)&Pp[TILE_HALVES + frag + kk * 16]; \
            acc = __builtin_amdgcn_mfma_f32_32x32x16_f16(af, bf, acc, 0, 0, 0); \
        } }

#pragma unroll
    for (int c = 0; c < 13; ++c) {
        _Float16 wq[6];
        int kb;
        compute_w(xs[c], kb, wq);                // VALU, overlaps other waves' LDS phase
        __syncthreads();
        // MFMA ds_reads first (prev buffer, ready), then scatter burst (cur buffer)
        if (c >= 1) DO_MFMA(smem + (((c & 1) ^ 1) * 2) * TILE_HALVES);
        _Float16* cur = smem + (c & 1) * 2 * TILE_HALVES + toff;
        if (c >= 2) zero6(cur, col, (c & 1) ? kbo1 : kbo0);
        scatter6(cur, col, kb, wq);
        if (c & 1) kbo1 = kb; else kbo0 = kb;
    }
    if (extra) {                                 // chunk 13 (P1), block-uniform branch
        _Float16 wq[6];
        int kb;
        compute_w(xs[13], kb, wq);
        __syncthreads();
        DO_MFMA(smem);                           // chunk 12 (P0)
        _Float16* cur = smem + 2 * TILE_HALVES + toff;
        zero6(cur, col, kbo1);
        scatter6(cur, col, kb, wq);
        __syncthreads();
        DO_MFMA(smem + 2 * TILE_HALVES);         // chunk 13 (P1)
    } else {
        __syncthreads();
        DO_MFMA(smem);                           // chunk 12 (P0)
    }
    __syncthreads();                             // all mfma reads done before smem reuse

    // block reduce: 4 waves hold K-split partials of the SAME 32x32.
    // C/D layout (32x32): col = lane&31, row = (reg&3) + 8*(reg>>2) + 4*(lane>>5)
    float* red = (float*)smem;                   // 4 * 1024 floats = 16 KB
    const int colc = lane & 31;
    const int rlo = 4 * (lane >> 5);
#pragma unroll
    for (int r = 0; r < 16; ++r) {
        int rowc = (r & 3) + 8 * (r >> 2) + rlo;
        red[wid * 1024 + rowc * 32 + colc] = acc[r];
    }
    __syncthreads();
    float* H = hist + ((size_t)(bx & (NSLOTS - 1)) * 2 + batch) * 1024;
    for (int idx = tid; idx < 1024; idx += NTHREADS) {
        float s = red[idx] + red[1024 + idx] + red[2048 + idx] + red[3072 + idx];
        atomicAdd(&H[idx], s);
    }

    // ---- last-block fused MI reduction ----
    __threadfence();                             // this block's hist atomics visible device-wide
    if (tid == 0) {
        int old = __hip_atomic_fetch_add(counter, 1, __ATOMIC_ACQ_REL, __HIP_MEMORY_SCOPE_AGENT);
        s_last = (old == NBLOCKS - 1);
    }
    __syncthreads();
    if (!s_last) return;

    // carve reducer scratch from smem (36992 B total)
    float* s_pab = (float*)smem;                                 // 2048 f = 8192 B
    double* s_pa = (double*)((char*)smem + 8192);                // 64 d  = 512 B
    double* s_pb = (double*)((char*)smem + 8704);                // 64 d  = 512 B
    double* s_red = (double*)((char*)smem + 9216);               // 256 d = 2048 B
    const double invN = 1.0 / (double)NVOX;

    __syncthreads();                             // red[] reads above are done (block-local)
    for (int idx = tid; idx < 2048; idx += NTHREADS) {
        float s = 0.0f;
        for (int sl = 0; sl < NSLOTS; ++sl)      // same order as before -> bit-identical
            s += __hip_atomic_load(&hist[sl * 2048 + idx], __ATOMIC_RELAXED,
                                   __HIP_MEMORY_SCOPE_AGENT);
        s_pab[idx] = s;
    }
    __syncthreads();

    if (tid < 64) {
        int b = tid >> 5, i = tid & 31;
        double s = 0.0;
        for (int j = 0; j < NBINS; ++j) s += (double)s_pab[(b * NBINS + i) * NBINS + j];
        s_pa[b * NBINS + i] = s * invN;
    } else if (tid < 128) {
        int t2 = tid - 64;
        int b = t2 >> 5, j = t2 & 31;
        double s = 0.0;
        for (int i = 0; i < NBINS; ++i) s += (double)s_pab[(b * NBINS + i) * NBINS + j];
        s_pb[b * NBINS + j] = s * invN;
    }
    __syncthreads();

    double accd = 0.0;
    for (int idx = tid; idx < 2048; idx += NTHREADS) {
        int b = idx >> 10;
        int cell = idx & 1023;
        int i = cell >> 5, j = cell & 31;
        double pab = (double)s_pab[idx] * invN;
        double papb = s_pa[b * NBINS + i] * s_pb[b * NBINS + j];
        accd += pab * log((pab + 1e-7) / (papb + 1e-7) + 1e-7);
    }
    s_red[tid] = accd;
    __syncthreads();
    for (int s2 = 128; s2 > 0; s2 >>= 1) {
        if (tid < s2) s_red[tid] += s_red[tid + s2];
        __syncthreads();
    }
    if (tid == 0) out[0] = (float)(-0.5 * s_red[0]);
}

extern "C" void kernel_launch(void* const* d_in, const int* in_sizes, int n_in,
                              void* d_out, int out_size, void* d_ws, size_t ws_size,
                              hipStream_t stream) {
    const float* pred = (const float*)d_in[0];
    const float* targ = (const float*)d_in[1];
    float* hist = (float*)d_ws;
    int* counter = (int*)((char*)d_ws + NSLOTS * 2048 * sizeof(float));
    float* out = (float*)d_out;

    hipMemsetAsync(d_ws, 0, NSLOTS * 2048 * sizeof(float) + 16, stream);
    dim3 grid(BPB, 2);
    hipLaunchKernelGGL(mi_hist_kernel, grid, dim3(NTHREADS), 0, stream,
                       pred, targ, hist, counter, out);
}

// Round 9
// 31.907 us; speedup vs baseline: 3.0334x; 3.0334x over previous
//
#include <hip/hip_runtime.h>
#include <hip/hip_bf16.h>

#define NBINS 32
#define CHUNK 128           // voxels per chunk per block
#define NROWS 34            // bins clamped to [-1,32] then +1 -> rows 0..33; rows 1..32 = bins 0..31
#define STR 136             // halfs per row; 272B stride, 16B-aligned, bank-uniform b128 reads
#define TILE_HALVES (NROWS * STR)   // 4624 halfs = 9248 B
#define NTHREADS 256
#define NVOX 884736         // 96^3 = 6912 * 128
#define BPB 512             // grid (512,2) = 1024 blocks = exactly 4/CU
#define NSLOTS 16

typedef __attribute__((ext_vector_type(8))) _Float16 half8;
typedef __attribute__((ext_vector_type(16))) float f32x16;
typedef __attribute__((ext_vector_type(4))) int i32x4;

// Parzen 6-tap window — BIT-IDENTICAL math to the validated R4-R7 kernels.
__device__ __forceinline__ void compute_w(float x, int& kb, _Float16* wq) {
    float tt = x * 31.0f;
    float kf = rintf(tt);
    int ki = (int)kf;
    float u = tt - kf;               // [-0.5, 0.5]
    kb = ki - 3 + (u > 0.0f ? 1 : 0);
    float w[6];
    float s = 0.0f;
#pragma unroll
    for (int o = 0; o < 6; ++o) {
        int b = kb + o;
        float d = tt - (float)b;
        float e = __expf(-2.0f * d * d);
        e = ((unsigned)b < NBINS) ? e : 0.0f;
        w[o] = e;
        s += e;
    }
    float rinv = 1.0f / s;
#pragma unroll
    for (int o = 0; o < 6; ++o) wq[o] = (_Float16)(w[o] * rinv);
}

// Scatter with clamped rows (OOB -> garbage rows 0/33, never read by MFMA).
// Saves the 6 LDS half-offsets so the stale-tap zeroing 2 chunks later
// reuses them (no re-clamp / re-mad).
__device__ __forceinline__ void scatter6_save(_Float16* __restrict__ L, int col, int kb,
                                              const _Float16* wq, int* adr) {
#pragma unroll
    for (int o = 0; o < 6; ++o) {
        int r = min(max(kb + o, -1), 32) + 1;
        int a = r * STR + col;
        adr[o] = a;
        L[a] = wq[o];
    }
}
__device__ __forceinline__ void zero6_adr(_Float16* __restrict__ L, const int* adr) {
#pragma unroll
    for (int o = 0; o < 6; ++o) L[adr[o]] = (_Float16)0.0f;
}

__global__ __launch_bounds__(NTHREADS, 4)
void mi_hist_kernel(const float* __restrict__ pred, const float* __restrict__ targ,
                    float* __restrict__ hist /* [NSLOTS][2][32][32] */) {
    // ping-pong buffers P0/P1, each = A tile + B tile
    __shared__ __attribute__((aligned(16))) _Float16 smem[4 * TILE_HALVES];

    const int tid = threadIdx.x;
    const int bx = blockIdx.x;
    const int batch = blockIdx.y;
    const int col = tid & 127;
    const bool isB = tid >= 128;                 // 0-127: pred tile, 128-255: targ tile
    const float* src = (isB ? targ : pred) + (size_t)batch * NVOX;
    const int toff = isB ? TILE_HALVES : 0;

    const int wid = tid >> 6;
    const int lane = tid & 63;
    // mfma_f32_32x32x16_f16: row(col)=lane&31 (bin b -> LDS row b+1), wave wid owns K [wid*32,+32)
    const int frag = (1 + (lane & 31)) * STR + wid * 32 + 8 * (lane >> 5);

    // preload ALL chunk values -> no vmem in the main loop (barriers drain nothing)
    float xs[14];
#pragma unroll
    for (int c = 0; c < 13; ++c)
        xs[c] = src[((size_t)(c * BPB + bx)) * CHUNK + col];
    const bool extra = (bx < 256);               // 6912 = 512*13 + 256, block-uniform
    if (extra) xs[13] = src[((size_t)(13 * BPB + bx)) * CHUNK + col];

    // zero all 4 tiles once
    {
        i32x4 z = {0, 0, 0, 0};
        i32x4* zp = (i32x4*)smem;
#pragma unroll
        for (int i = 0; i < 10; ++i) {
            int idx = i * NTHREADS + tid;
            if (idx < (4 * TILE_HALVES) / 8) zp[idx] = z;
        }
    }

    f32x16 acc;
#pragma unroll
    for (int r = 0; r < 16; ++r) acc[r] = 0.0f;

    int adr[2][6];   // saved scatter offsets per parity; all accesses compile-time indexed

#define DO_MFMA(BASE) { \
        const _Float16* Pp = (BASE); \
        _Pragma("unroll") \
        for (int kk = 0; kk < 2; ++kk) { \
            half8 af = *(const half8*)&Pp[frag + kk * 16]; \
            half8 bf = *(const half8*)&Pp[TILE_HALVES + frag + kk * 16]; \
            acc = __builtin_amdgcn_mfma_f32_32x32x16_f16(af, bf, acc, 0, 0, 0); \
        } }

#pragma unroll
    for (int c = 0; c < 13; ++c) {
        _Float16 wq[6];
        int kb;
        compute_w(xs[c], kb, wq);                // VALU, overlaps other waves' LDS phase
        __syncthreads();
        // MFMA ds_reads first (prev buffer, ready; in-order DS queue -> reads
        // complete before the write burst), then scatter into cur buffer
        if (c >= 1) DO_MFMA(smem + (((c & 1) ^ 1) * 2) * TILE_HALVES);
        _Float16* cur = smem + (c & 1) * 2 * TILE_HALVES + toff;
        if (c >= 2) zero6_adr(cur, adr[c & 1]);  // stale taps from chunk c-2, saved addrs
        scatter6_save(cur, col, kb, wq, adr[c & 1]);
    }
    if (extra) {                                 // chunk 13 (P1), block-uniform branch
        _Float16 wq[6];
        int kb;
        compute_w(xs[13], kb, wq);
        __syncthreads();
        DO_MFMA(smem);                           // chunk 12 (P0)
        _Float16* cur = smem + 2 * TILE_HALVES + toff;
        zero6_adr(cur, adr[1]);
        scatter6_save(cur, col, kb, wq, adr[1]);
        __syncthreads();
        DO_MFMA(smem + 2 * TILE_HALVES);         // chunk 13 (P1)
    } else {
        __syncthreads();
        DO_MFMA(smem);                           // chunk 12 (P0)
    }
    __syncthreads();                             // all mfma reads done before smem reuse

    // block reduce: 4 waves hold K-split partials of the SAME 32x32.
    // C/D layout (32x32): col = lane&31, row = (reg&3) + 8*(reg>>2) + 4*(lane>>5)
    float* red = (float*)smem;                   // 4 * 1024 floats = 16 KB
    const int colc = lane & 31;
    const int rlo = 4 * (lane >> 5);
#pragma unroll
    for (int r = 0; r < 16; ++r) {
        int rowc = (r & 3) + 8 * (r >> 2) + rlo;
        red[wid * 1024 + rowc * 32 + colc] = acc[r];
    }
    __syncthreads();
    float* H = hist + ((size_t)(bx & (NSLOTS - 1)) * 2 + batch) * 1024;
    for (int idx = tid; idx < 1024; idx += NTHREADS) {
        float s = red[idx] + red[1024 + idx] + red[2048 + idx] + red[3072 + idx];
        atomicAdd(&H[idx], s);
    }
}

__global__ void mi_reduce_kernel(const float* __restrict__ hist, float* __restrict__ out) {
    __shared__ float s_pab[2 * NBINS * NBINS];
    __shared__ double s_pa[2][NBINS];
    __shared__ double s_pb[2][NBINS];
    __shared__ double s_red[256];
    const int tid = threadIdx.x;
    const double invN = 1.0 / (double)NVOX;

    for (int g = tid; g < 512; g += 256) {
        float4 s = make_float4(0.f, 0.f, 0.f, 0.f);
        for (int sl = 0; sl < NSLOTS; ++sl) {
            float4 v = ((const float4*)hist)[sl * 512 + g];
            s.x += v.x; s.y += v.y; s.z += v.z; s.w += v.w;
        }
        ((float4*)s_pab)[g] = s;
    }
    __syncthreads();

    if (tid < 64) {
        int b = tid >> 5, i = tid & 31;
        double s = 0.0;
        for (int j = 0; j < NBINS; ++j) s += (double)s_pab[(b * NBINS + i) * NBINS + j];
        s_pa[b][i] = s * invN;
    } else if (tid < 128) {
        int t2 = tid - 64;
        int b = t2 >> 5, j = t2 & 31;
        double s = 0.0;
        for (int i = 0; i < NBINS; ++i) s += (double)s_pab[(b * NBINS + i) * NBINS + j];
        s_pb[b][j] = s * invN;
    }
    __syncthreads();

    double acc = 0.0;
    for (int idx = tid; idx < 2 * NBINS * NBINS; idx += 256) {
        int b = idx >> 10;
        int cell = idx & 1023;
        int i = cell >> 5, j = cell & 31;
        double pab = (double)s_pab[idx] * invN;
        double papb = s_pa[b][i] * s_pb[b][j];
        acc += pab * log((pab + 1e-7) / (papb + 1e-7) + 1e-7);
    }
    s_red[tid] = acc;
    __syncthreads();
    for (int s2 = 128; s2 > 0; s2 >>= 1) {
        if (tid < s2) s_red[tid] += s_red[tid + s2];
        __syncthreads();
    }
    if (tid == 0) out[0] = (float)(-0.5 * s_red[0]);
}

extern "C" void kernel_launch(void* const* d_in, const int* in_sizes, int n_in,
                              void* d_out, int out_size, void* d_ws, size_t ws_size,
                              hipStream_t stream) {
    const float* pred = (const float*)d_in[0];
    const float* targ = (const float*)d_in[1];
    float* hist = (float*)d_ws;
    float* out = (float*)d_out;

    hipMemsetAsync(hist, 0, NSLOTS * 2 * NBINS * NBINS * sizeof(float), stream);
    dim3 grid(BPB, 2);
    hipLaunchKernelGGL(mi_hist_kernel, grid, dim3(NTHREADS), 0, stream, pred, targ, hist);
    hipLaunchKernelGGL(mi_reduce_kernel, dim3(1), dim3(256), 0, stream, hist, out);
}